// Round 1
// baseline (1317.591 us; speedup 1.0000x reference)
//
#include <hip/hip_runtime.h>
#include <math.h>

#define NN 50000
#define EE 500000
#define DIN 128
#define HH 256
#define PP 100000

// ---------------- CSR build ----------------

__global__ __launch_bounds__(256) void count_deg(const int* __restrict__ dst,
                                                 int* __restrict__ cnt, int n) {
  int i = blockIdx.x * 256 + threadIdx.x;
  if (i < n) atomicAdd(&cnt[dst[i]], 1);
}

__global__ __launch_bounds__(256) void compute_dinv(const int* __restrict__ cnt,
                                                    float* __restrict__ dinv, int n) {
  int i = blockIdx.x * 256 + threadIdx.x;
  if (i < n) dinv[i] = rsqrtf((float)(cnt[i] + 1));  // +1 self-loop; deg>=1 always
}

__global__ __launch_bounds__(256) void scan_block(const int* __restrict__ cnt,
                                                  int* __restrict__ outp,
                                                  int* __restrict__ bsum, int n) {
  __shared__ int s[256];
  int i = blockIdx.x * 256 + threadIdx.x;
  int v = (i < n) ? cnt[i] : 0;
  s[threadIdx.x] = v;
  __syncthreads();
  for (int off = 1; off < 256; off <<= 1) {
    int t = (threadIdx.x >= off) ? s[threadIdx.x - off] : 0;
    __syncthreads();
    s[threadIdx.x] += t;
    __syncthreads();
  }
  if (i < n) outp[i] = s[threadIdx.x] - v;  // exclusive within block
  if (threadIdx.x == 255) bsum[blockIdx.x] = s[255];
}

__global__ void scan_totals(int* bsum, int nb) {
  if (threadIdx.x == 0 && blockIdx.x == 0) {
    int run = 0;
    for (int i = 0; i < nb; ++i) { int t = bsum[i]; bsum[i] = run; run += t; }
  }
}

__global__ __launch_bounds__(256) void scan_add(int* __restrict__ indptr,
                                                const int* __restrict__ bsum,
                                                const int* __restrict__ cnt, int n) {
  int i = blockIdx.x * 256 + threadIdx.x;
  if (i < n) {
    int v = indptr[i] + bsum[blockIdx.x];
    indptr[i] = v;
    if (i == n - 1) indptr[n] = v + cnt[i];
  }
}

__global__ __launch_bounds__(256) void fill_csr(const int* __restrict__ src,
                                                const int* __restrict__ dst,
                                                const int* __restrict__ indptr,
                                                int* __restrict__ fill,
                                                int* __restrict__ col, int n) {
  int i = blockIdx.x * 256 + threadIdx.x;
  if (i < n) {
    int d = dst[i];
    int p = atomicAdd(&fill[d], 1);
    col[indptr[d] + p] = src[i];
  }
}

// ---------------- dense GEMM: C[M][256] = X[M][K] @ W[K][256] ----------------
// block: 64 rows x 256 cols, 256 threads, each thread 4 rows x 16 cols (4 float4)

__global__ __launch_bounds__(256) void gemm_xw(const float* __restrict__ X,
                                               const float* __restrict__ W,
                                               float* __restrict__ C, int M, int K) {
  __shared__ __align__(16) float As[64][36];   // 32-wide K tile, pad to 36 (16B-aligned rows)
  __shared__ float4 B4s[32 * 64];              // 32 x 256 floats
  int tid = threadIdx.x;
  int ty = tid >> 4, tx = tid & 15;
  int blkRow = blockIdx.x * 64;
  float4 acc[4][4];
#pragma unroll
  for (int r = 0; r < 4; ++r)
#pragma unroll
    for (int c = 0; c < 4; ++c) acc[r][c] = make_float4(0.f, 0.f, 0.f, 0.f);

  for (int kt = 0; kt < K; kt += 32) {
    {  // stage A tile [64][32]
      int r = tid >> 3, v4 = tid & 7;
      int gr0 = blkRow + r, gr1 = blkRow + r + 32;
      float4 z = make_float4(0.f, 0.f, 0.f, 0.f);
      float4 a0 = (gr0 < M) ? *(const float4*)(X + (size_t)gr0 * K + kt + v4 * 4) : z;
      float4 a1 = (gr1 < M) ? *(const float4*)(X + (size_t)gr1 * K + kt + v4 * 4) : z;
      *(float4*)&As[r][v4 * 4] = a0;
      *(float4*)&As[r + 32][v4 * 4] = a1;
    }
    {  // stage B tile [32][256]
      const float4* W4 = (const float4*)(W + (size_t)kt * HH);
#pragma unroll
      for (int i = 0; i < 8; ++i) B4s[tid + 256 * i] = W4[tid + 256 * i];
    }
    __syncthreads();
#pragma unroll 8
    for (int k = 0; k < 32; ++k) {
      float a0 = As[ty * 4 + 0][k];
      float a1 = As[ty * 4 + 1][k];
      float a2 = As[ty * 4 + 2][k];
      float a3 = As[ty * 4 + 3][k];
#pragma unroll
      for (int c = 0; c < 4; ++c) {
        float4 b = B4s[k * 64 + tx + 16 * c];
        acc[0][c].x += a0 * b.x; acc[0][c].y += a0 * b.y; acc[0][c].z += a0 * b.z; acc[0][c].w += a0 * b.w;
        acc[1][c].x += a1 * b.x; acc[1][c].y += a1 * b.y; acc[1][c].z += a1 * b.z; acc[1][c].w += a1 * b.w;
        acc[2][c].x += a2 * b.x; acc[2][c].y += a2 * b.y; acc[2][c].z += a2 * b.z; acc[2][c].w += a2 * b.w;
        acc[3][c].x += a3 * b.x; acc[3][c].y += a3 * b.y; acc[3][c].z += a3 * b.z; acc[3][c].w += a3 * b.w;
      }
    }
    __syncthreads();
  }
#pragma unroll
  for (int r = 0; r < 4; ++r) {
    int row = blkRow + ty * 4 + r;
    if (row < M) {
#pragma unroll
      for (int c = 0; c < 4; ++c)
        *(float4*)(C + (size_t)row * HH + tx * 4 + 64 * c) = acc[r][c];
    }
  }
}

// ---------------- CSR gather aggregate: out = relu(dinv_i*(sum dinv_s*h_s + dinv_i*h_i) + b) ----
// one wave (64 lanes) per node; lane owns 4 contiguous features (float4)

__global__ __launch_bounds__(256) void aggregate(const float* __restrict__ h,
                                                 const int* __restrict__ indptr,
                                                 const int* __restrict__ col,
                                                 const float* __restrict__ dinv,
                                                 const float* __restrict__ bias,
                                                 float* __restrict__ out, int n) {
  int gw = (blockIdx.x * 256 + threadIdx.x) >> 6;
  int lane = threadIdx.x & 63;
  if (gw >= n) return;
  int beg = indptr[gw], end = indptr[gw + 1];
  float di = dinv[gw];
  float4 acc = make_float4(0.f, 0.f, 0.f, 0.f);
  for (int e = beg; e < end; ++e) {
    int s = col[e];
    float ds = dinv[s];
    float4 hv = *(const float4*)(h + (size_t)s * HH + lane * 4);
    acc.x += ds * hv.x; acc.y += ds * hv.y; acc.z += ds * hv.z; acc.w += ds * hv.w;
  }
  float4 hv = *(const float4*)(h + (size_t)gw * HH + lane * 4);
  acc.x += di * hv.x; acc.y += di * hv.y; acc.z += di * hv.z; acc.w += di * hv.w;
  float4 bv = *(const float4*)(bias + lane * 4);
  float4 o;
  o.x = fmaxf(fmaf(di, acc.x, bv.x), 0.f);
  o.y = fmaxf(fmaf(di, acc.y, bv.y), 0.f);
  o.z = fmaxf(fmaf(di, acc.z, bv.z), 0.f);
  o.w = fmaxf(fmaf(di, acc.w, bv.w), 0.f);
  *(float4*)(out + (size_t)gw * HH + lane * 4) = o;
}

// ---------------- fused pair MLP ----------------
// per block: 64 pairs. hidden = relu(concat(xl[y0],xr[y1]) @ fcW + fcb); out = sigmoid(hidden . w2 + b2)

__global__ __launch_bounds__(256) void mlp_fused(const float* __restrict__ XL,
                                                 const float* __restrict__ XR,
                                                 const int* __restrict__ y,
                                                 const float* __restrict__ fcW,
                                                 const float* __restrict__ fcb,
                                                 const float* __restrict__ w2,
                                                 const float* __restrict__ b2,
                                                 float* __restrict__ out, int P) {
  __shared__ __align__(16) float As[64][36];
  __shared__ float4 B4s[32 * 64];
  __shared__ int yl[64], yr[64];
  __shared__ float red[64][17];
  int tid = threadIdx.x;
  int ty = tid >> 4, tx = tid & 15;
  int p0 = blockIdx.x * 64;
  if (tid < 64) {
    int p = p0 + tid;
    yl[tid] = (p < P) ? y[2 * p] : 0;
    yr[tid] = (p < P) ? y[2 * p + 1] : 0;
  }
  __syncthreads();
  float4 acc[4][4];
#pragma unroll
  for (int r = 0; r < 4; ++r)
#pragma unroll
    for (int c = 0; c < 4; ++c) acc[r][c] = make_float4(0.f, 0.f, 0.f, 0.f);

  for (int kt = 0; kt < 16; ++kt) {  // K = 512, tiles of 32; kt<8 -> XL half, else XR half
    {
      int r = tid >> 3, v4 = tid & 7;
      int kg = kt * 32 + v4 * 4;
      const float* base = (kt < 8) ? XL : XR;
      int kk = (kt < 8) ? kg : kg - 256;
      int n0 = (kt < 8) ? yl[r] : yr[r];
      int n1 = (kt < 8) ? yl[r + 32] : yr[r + 32];
      float4 a0 = *(const float4*)(base + (size_t)n0 * HH + kk);
      float4 a1 = *(const float4*)(base + (size_t)n1 * HH + kk);
      *(float4*)&As[r][v4 * 4] = a0;
      *(float4*)&As[r + 32][v4 * 4] = a1;
    }
    {
      const float4* W4 = (const float4*)(fcW + (size_t)kt * 32 * HH);
#pragma unroll
      for (int i = 0; i < 8; ++i) B4s[tid + 256 * i] = W4[tid + 256 * i];
    }
    __syncthreads();
#pragma unroll 8
    for (int k = 0; k < 32; ++k) {
      float a0 = As[ty * 4 + 0][k];
      float a1 = As[ty * 4 + 1][k];
      float a2 = As[ty * 4 + 2][k];
      float a3 = As[ty * 4 + 3][k];
#pragma unroll
      for (int c = 0; c < 4; ++c) {
        float4 b = B4s[k * 64 + tx + 16 * c];
        acc[0][c].x += a0 * b.x; acc[0][c].y += a0 * b.y; acc[0][c].z += a0 * b.z; acc[0][c].w += a0 * b.w;
        acc[1][c].x += a1 * b.x; acc[1][c].y += a1 * b.y; acc[1][c].z += a1 * b.z; acc[1][c].w += a1 * b.w;
        acc[2][c].x += a2 * b.x; acc[2][c].y += a2 * b.y; acc[2][c].z += a2 * b.z; acc[2][c].w += a2 * b.w;
        acc[3][c].x += a3 * b.x; acc[3][c].y += a3 * b.y; acc[3][c].z += a3 * b.z; acc[3][c].w += a3 * b.w;
      }
    }
    __syncthreads();
  }
  // epilogue: bias + relu + dot with w2, reduce across the 16 tx threads per row
  const float4* fcb4 = (const float4*)fcb;
  const float4* w24 = (const float4*)w2;
  float part[4] = {0.f, 0.f, 0.f, 0.f};
#pragma unroll
  for (int c = 0; c < 4; ++c) {
    int cc = tx + 16 * c;
    float4 bv = fcb4[cc];
    float4 wv = w24[cc];
#pragma unroll
    for (int r = 0; r < 4; ++r) {
      float4 v = acc[r][c];
      part[r] += fmaxf(v.x + bv.x, 0.f) * wv.x + fmaxf(v.y + bv.y, 0.f) * wv.y +
                 fmaxf(v.z + bv.z, 0.f) * wv.z + fmaxf(v.w + bv.w, 0.f) * wv.w;
    }
  }
#pragma unroll
  for (int r = 0; r < 4; ++r) red[ty * 4 + r][tx] = part[r];
  __syncthreads();
  if (tid < 64) {
    float s = 0.f;
#pragma unroll
    for (int j = 0; j < 16; ++j) s += red[tid][j];
    int p = p0 + tid;
    if (p < P) out[p] = 1.f / (1.f + expf(-(s + b2[0])));
  }
}

// ---------------- launch ----------------

extern "C" void kernel_launch(void* const* d_in, const int* in_sizes, int n_in,
                              void* d_out, int out_size, void* d_ws, size_t ws_size,
                              hipStream_t stream) {
  const float* x_s  = (const float*)d_in[0];
  const float* x_t  = (const float*)d_in[1];
  const int*   ei_s = (const int*)d_in[2];   // [2,E]: src then dst
  const int*   ei_t = (const int*)d_in[3];
  const int*   y    = (const int*)d_in[4];   // [P,2]
  const float* W1   = (const float*)d_in[5];
  const float* b1   = (const float*)d_in[6];
  const float* W2   = (const float*)d_in[7];
  const float* b2   = (const float*)d_in[8];
  const float* fcW  = (const float*)d_in[9];
  const float* fcb  = (const float*)d_in[10];
  const float* fc2W = (const float*)d_in[11];
  const float* fc2b = (const float*)d_in[12];
  float* out = (float*)d_out;

  char* ws = (char*)d_ws;
  size_t off = 0;
  auto alloc = [&](size_t bytes) -> void* {
    void* p = ws + off;
    off += (bytes + 255) & ~(size_t)255;
    return p;
  };
  float* bufG   = (float*)alloc((size_t)NN * HH * 4);  // GEMM output h
  float* bufT   = (float*)alloc((size_t)NN * HH * 4);  // layer-1 conv output
  float* bufL   = (float*)alloc((size_t)NN * HH * 4);  // xl (final s-tower)
  float* bufR   = (float*)alloc((size_t)NN * HH * 4);  // xr (final t-tower)
  int* cnt_s    = (int*)alloc((size_t)NN * 4);
  int* cnt_t    = (int*)alloc((size_t)NN * 4);
  float* dinv_s = (float*)alloc((size_t)NN * 4);
  float* dinv_t = (float*)alloc((size_t)NN * 4);
  int* indptr_s = (int*)alloc((size_t)(NN + 1) * 4);
  int* indptr_t = (int*)alloc((size_t)(NN + 1) * 4);
  int* fill_s   = (int*)alloc((size_t)NN * 4);
  int* fill_t   = (int*)alloc((size_t)NN * 4);
  int* col_s    = (int*)alloc((size_t)EE * 4);
  int* col_t    = (int*)alloc((size_t)EE * 4);
  int* bsum     = (int*)alloc(1024 * 4);

  hipMemsetAsync(cnt_s, 0, (size_t)NN * 4, stream);
  hipMemsetAsync(cnt_t, 0, (size_t)NN * 4, stream);
  hipMemsetAsync(fill_s, 0, (size_t)NN * 4, stream);
  hipMemsetAsync(fill_t, 0, (size_t)NN * 4, stream);

  const int NB = (NN + 255) / 256;   // 196
  const int EB = (EE + 255) / 256;   // 1954

  // s graph CSR + dinv
  count_deg<<<EB, 256, 0, stream>>>(ei_s + EE, cnt_s, EE);
  compute_dinv<<<NB, 256, 0, stream>>>(cnt_s, dinv_s, NN);
  scan_block<<<NB, 256, 0, stream>>>(cnt_s, indptr_s, bsum, NN);
  scan_totals<<<1, 1, 0, stream>>>(bsum, NB);
  scan_add<<<NB, 256, 0, stream>>>(indptr_s, bsum, cnt_s, NN);
  fill_csr<<<EB, 256, 0, stream>>>(ei_s, ei_s + EE, indptr_s, fill_s, col_s, EE);
  // t graph CSR + dinv
  count_deg<<<EB, 256, 0, stream>>>(ei_t + EE, cnt_t, EE);
  compute_dinv<<<NB, 256, 0, stream>>>(cnt_t, dinv_t, NN);
  scan_block<<<NB, 256, 0, stream>>>(cnt_t, indptr_t, bsum, NN);
  scan_totals<<<1, 1, 0, stream>>>(bsum, NB);
  scan_add<<<NB, 256, 0, stream>>>(indptr_t, bsum, cnt_t, NN);
  fill_csr<<<EB, 256, 0, stream>>>(ei_t, ei_t + EE, indptr_t, fill_t, col_t, EE);

  const int GB = (NN + 63) / 64;         // 782
  const int AB = (NN * 64 + 255) / 256;  // 12500 (1 wave per node)

  // s tower
  gemm_xw<<<GB, 256, 0, stream>>>(x_s, W1, bufG, NN, DIN);
  aggregate<<<AB, 256, 0, stream>>>(bufG, indptr_s, col_s, dinv_s, b1, bufT, NN);
  gemm_xw<<<GB, 256, 0, stream>>>(bufT, W2, bufG, NN, HH);
  aggregate<<<AB, 256, 0, stream>>>(bufG, indptr_s, col_s, dinv_s, b2, bufL, NN);
  // t tower
  gemm_xw<<<GB, 256, 0, stream>>>(x_t, W1, bufG, NN, DIN);
  aggregate<<<AB, 256, 0, stream>>>(bufG, indptr_t, col_t, dinv_t, b1, bufT, NN);
  gemm_xw<<<GB, 256, 0, stream>>>(bufT, W2, bufG, NN, HH);
  aggregate<<<AB, 256, 0, stream>>>(bufG, indptr_t, col_t, dinv_t, b2, bufR, NN);
  // fused pair MLP
  mlp_fused<<<(PP + 63) / 64, 256, 0, stream>>>(bufL, bufR, y, fcW, fcb, fc2W, fc2b, out, PP);
}

// Round 4
// 918.826 us; speedup vs baseline: 1.4340x; 1.4340x over previous
//
#include <hip/hip_runtime.h>
#include <math.h>

#define NN 50000
#define EE 500000
#define DIN 128
#define HH 256
#define PP 100000

typedef unsigned short ushortT;
typedef short bf16x8 __attribute__((ext_vector_type(8)));   // 8 bf16 in 4 VGPRs
typedef float f32x4 __attribute__((ext_vector_type(4)));

// ---- bf16 helpers (RNE) ----
__device__ __forceinline__ ushortT f2bf(float f) {
  unsigned u = __float_as_uint(f);
  unsigned r = u + 0x7FFFu + ((u >> 16) & 1u);
  return (ushortT)(r >> 16);
}
__device__ __forceinline__ float bf2f(ushortT h) {
  return __uint_as_float(((unsigned)h) << 16);
}

// async global->LDS, 16B per lane. LDS dest must be wave-uniform base (+lane*16 implicit).
__device__ __forceinline__ void gld16(const void* g, void* l) {
  __builtin_amdgcn_global_load_lds((const __attribute__((address_space(1))) void*)g,
                                   (__attribute__((address_space(3))) void*)l, 16, 0, 0);
}

// ---------------- CSR build ----------------

__global__ __launch_bounds__(256) void count_deg(const int* __restrict__ dst,
                                                 int* __restrict__ cnt, int n) {
  int i = blockIdx.x * 256 + threadIdx.x;
  if (i < n) atomicAdd(&cnt[dst[i]], 1);
}

__global__ __launch_bounds__(256) void compute_dinv(const int* __restrict__ cnt,
                                                    float* __restrict__ dinv, int n) {
  int i = blockIdx.x * 256 + threadIdx.x;
  if (i < n) dinv[i] = rsqrtf((float)(cnt[i] + 1));  // +1 self-loop
}

__global__ __launch_bounds__(256) void scan_block(const int* __restrict__ cnt,
                                                  int* __restrict__ outp,
                                                  int* __restrict__ bsum, int n) {
  __shared__ int s[256];
  int i = blockIdx.x * 256 + threadIdx.x;
  int v = (i < n) ? cnt[i] : 0;
  s[threadIdx.x] = v;
  __syncthreads();
  for (int off = 1; off < 256; off <<= 1) {
    int t = (threadIdx.x >= off) ? s[threadIdx.x - off] : 0;
    __syncthreads();
    s[threadIdx.x] += t;
    __syncthreads();
  }
  if (i < n) outp[i] = s[threadIdx.x] - v;
  if (threadIdx.x == 255) bsum[blockIdx.x] = s[255];
}

__global__ void scan_totals(int* bsum, int nb) {
  if (threadIdx.x == 0 && blockIdx.x == 0) {
    int run = 0;
    for (int i = 0; i < nb; ++i) { int t = bsum[i]; bsum[i] = run; run += t; }
  }
}

__global__ __launch_bounds__(256) void scan_add(int* __restrict__ indptr,
                                                const int* __restrict__ bsum,
                                                const int* __restrict__ cnt, int n) {
  int i = blockIdx.x * 256 + threadIdx.x;
  if (i < n) {
    int v = indptr[i] + bsum[blockIdx.x];
    indptr[i] = v;
    if (i == n - 1) indptr[n] = v + cnt[i];
  }
}

__global__ __launch_bounds__(256) void fill_csr(const int* __restrict__ src,
                                                const int* __restrict__ dst,
                                                const int* __restrict__ indptr,
                                                int* __restrict__ fill,
                                                int* __restrict__ col, int n) {
  int i = blockIdx.x * 256 + threadIdx.x;
  if (i < n) {
    int d = dst[i];
    int p = atomicAdd(&fill[d], 1);
    col[indptr[d] + p] = src[i];
  }
}

// ---------------- precision-split kernels ----------------

// x fp32 -> hi/lo bf16 (elementwise, 4 per thread)
__global__ __launch_bounds__(256) void split_x(const float* __restrict__ x,
                                               ushortT* __restrict__ hi,
                                               ushortT* __restrict__ lo, int n4) {
  int i = blockIdx.x * 256 + threadIdx.x;
  if (i >= n4) return;
  float4 v = ((const float4*)x)[i];
  ushort4 h, l;
  h.x = f2bf(v.x); l.x = f2bf(v.x - bf2f(h.x));
  h.y = f2bf(v.y); l.y = f2bf(v.y - bf2f(h.y));
  h.z = f2bf(v.z); l.z = f2bf(v.z - bf2f(h.z));
  h.w = f2bf(v.w); l.w = f2bf(v.w - bf2f(h.w));
  ((ushort4*)hi)[i] = h;
  ((ushort4*)lo)[i] = l;
}

// W [K][256] fp32 -> Wt hi/lo [256][K] bf16 (transpose + split), tiny
__global__ __launch_bounds__(256) void split_w_t(const float* __restrict__ W,
                                                 ushortT* __restrict__ Whi,
                                                 ushortT* __restrict__ Wlo, int K) {
  int idx = blockIdx.x * 256 + threadIdx.x;
  if (idx >= K * 256) return;
  int k = idx >> 8, n = idx & 255;
  float v = W[idx];
  ushortT h = f2bf(v);
  Whi[(size_t)n * K + k] = h;
  Wlo[(size_t)n * K + k] = f2bf(v - bf2f(h));
}

// ---------------- MFMA GEMM: C[M][256] = (Ahi+Alo)[M][K] @ (Whi+Wlo)^T ----------------
// 256 threads = 4 waves; block tile 64 rows x 256 cols; wave w owns rows w*16..w*16+15.
// K-chunk 32. LDS fragment-major: A region 2x4KB, B region 2x16KB = 40KB.
// bf16x3: C = Ah*Bh + Al*Bh + Ah*Bl.

__global__ __launch_bounds__(256) void gemm_mfma(const ushortT* __restrict__ Ahi,
                                                 const ushortT* __restrict__ Alo,
                                                 const ushortT* __restrict__ Bhi,
                                                 const ushortT* __restrict__ Blo,
                                                 float* __restrict__ C, int M, int K) {
  __shared__ __align__(16) unsigned char smem[40960];
  int tid = threadIdx.x;
  int w = tid >> 6, l = tid & 63;
  int row0 = blockIdx.x * 64;

  f32x4 acc[16];
#pragma unroll
  for (int c = 0; c < 16; ++c) acc[c] = (f32x4)(0.f);

  int arow = w * 16 + (l & 15);
  int akg = l >> 4;
  int grow = row0 + arow;
  if (grow >= M) grow = M - 1;
  const size_t abase = (size_t)grow * K + akg * 8;
  size_t bkoff = (size_t)(l >> 4) * 8;

  for (int k0 = 0; k0 < K; k0 += 32) {
    // stage A (hi,lo): wave-uniform LDS bases
    gld16(Ahi + abase + k0, smem + w * 1024);
    gld16(Alo + abase + k0, smem + 4096 + w * 1024);
    // stage B (hi,lo): 4 rounds each
#pragma unroll
    for (int r = 0; r < 4; ++r) {
      int col = (r * 4 + w) * 16 + (l & 15);
      size_t boff = (size_t)col * K + k0 + bkoff;
      gld16(Bhi + boff, smem + 8192 + r * 4096 + w * 1024);
      gld16(Blo + boff, smem + 24576 + r * 4096 + w * 1024);
    }
    __syncthreads();
    bf16x8 ah = *(const bf16x8*)(smem + tid * 16);
    bf16x8 al = *(const bf16x8*)(smem + 4096 + tid * 16);
#pragma unroll
    for (int c = 0; c < 16; ++c) {
      bf16x8 bh = *(const bf16x8*)(smem + 8192 + (c * 64 + l) * 16);
      bf16x8 bl = *(const bf16x8*)(smem + 24576 + (c * 64 + l) * 16);
      acc[c] = __builtin_amdgcn_mfma_f32_16x16x32_bf16(ah, bh, acc[c], 0, 0, 0);
      acc[c] = __builtin_amdgcn_mfma_f32_16x16x32_bf16(al, bh, acc[c], 0, 0, 0);
      acc[c] = __builtin_amdgcn_mfma_f32_16x16x32_bf16(ah, bl, acc[c], 0, 0, 0);
    }
    __syncthreads();
  }
  // store: C[w*16 + (l>>4)*4 + r][c*16 + (l&15)]
  int orow = row0 + w * 16 + (l >> 4) * 4;
#pragma unroll
  for (int r = 0; r < 4; ++r) {
    int rr = orow + r;
    if (rr < M) {
#pragma unroll
      for (int c = 0; c < 16; ++c)
        C[(size_t)rr * HH + c * 16 + (l & 15)] = acc[c][r];
    }
  }
}

// ---------------- CSR gather aggregate -> bf16 hi/lo output ----------------
// out = relu(dinv_i*(sum dinv_s*h_s + dinv_i*h_i) + b); one wave per node, lane = 4 feats.

__global__ __launch_bounds__(256) void aggregate_bf(const float* __restrict__ h,
                                                    const int* __restrict__ indptr,
                                                    const int* __restrict__ col,
                                                    const float* __restrict__ dinv,
                                                    const float* __restrict__ bias,
                                                    ushortT* __restrict__ ohi,
                                                    ushortT* __restrict__ olo, int n) {
  int gw = (blockIdx.x * 256 + threadIdx.x) >> 6;
  int lane = threadIdx.x & 63;
  if (gw >= n) return;
  int beg = indptr[gw], end = indptr[gw + 1];
  float di = dinv[gw];
  float4 acc = make_float4(0.f, 0.f, 0.f, 0.f);
  int e = beg;
  for (; e + 4 <= end; e += 4) {
    int s0 = col[e], s1 = col[e + 1], s2 = col[e + 2], s3 = col[e + 3];
    float d0 = dinv[s0], d1 = dinv[s1], d2 = dinv[s2], d3 = dinv[s3];
    float4 h0 = *(const float4*)(h + (size_t)s0 * HH + lane * 4);
    float4 h1 = *(const float4*)(h + (size_t)s1 * HH + lane * 4);
    float4 h2 = *(const float4*)(h + (size_t)s2 * HH + lane * 4);
    float4 h3 = *(const float4*)(h + (size_t)s3 * HH + lane * 4);
    acc.x += d0 * h0.x + d1 * h1.x + d2 * h2.x + d3 * h3.x;
    acc.y += d0 * h0.y + d1 * h1.y + d2 * h2.y + d3 * h3.y;
    acc.z += d0 * h0.z + d1 * h1.z + d2 * h2.z + d3 * h3.z;
    acc.w += d0 * h0.w + d1 * h1.w + d2 * h2.w + d3 * h3.w;
  }
  for (; e < end; ++e) {
    int s = col[e];
    float ds = dinv[s];
    float4 hv = *(const float4*)(h + (size_t)s * HH + lane * 4);
    acc.x += ds * hv.x; acc.y += ds * hv.y; acc.z += ds * hv.z; acc.w += ds * hv.w;
  }
  float4 hv = *(const float4*)(h + (size_t)gw * HH + lane * 4);
  acc.x += di * hv.x; acc.y += di * hv.y; acc.z += di * hv.z; acc.w += di * hv.w;
  const float4 bv = *(const float4*)(bias + lane * 4);
  float o0 = fmaxf(fmaf(di, acc.x, bv.x), 0.f);
  float o1 = fmaxf(fmaf(di, acc.y, bv.y), 0.f);
  float o2 = fmaxf(fmaf(di, acc.z, bv.z), 0.f);
  float o3 = fmaxf(fmaf(di, acc.w, bv.w), 0.f);
  ushort4 hvec, lvec;
  hvec.x = f2bf(o0); lvec.x = f2bf(o0 - bf2f(hvec.x));
  hvec.y = f2bf(o1); lvec.y = f2bf(o1 - bf2f(hvec.y));
  hvec.z = f2bf(o2); lvec.z = f2bf(o2 - bf2f(hvec.z));
  hvec.w = f2bf(o3); lvec.w = f2bf(o3 - bf2f(hvec.w));
  *(ushort4*)(ohi + (size_t)gw * HH + lane * 4) = hvec;
  *(ushort4*)(olo + (size_t)gw * HH + lane * 4) = lvec;
}

// ---------------- fused pair MLP (MFMA) ----------------
// A row p = concat(xl[y0[p]], xr[y1[p]]) [512]; hidden = relu(A@fcW + fcb); out = sigmoid(hidden.w2 + b2)

__global__ __launch_bounds__(256) void mlp_mfma(const ushortT* __restrict__ XLhi,
                                                const ushortT* __restrict__ XLlo,
                                                const ushortT* __restrict__ XRhi,
                                                const ushortT* __restrict__ XRlo,
                                                const int* __restrict__ y,
                                                const ushortT* __restrict__ Bhi,
                                                const ushortT* __restrict__ Blo,
                                                const float* __restrict__ fcb,
                                                const float* __restrict__ w2,
                                                const float* __restrict__ b2,
                                                float* __restrict__ out, int P) {
  __shared__ __align__(16) unsigned char smem[40960];
  __shared__ int ynode[2][64];
  int tid = threadIdx.x;
  int w = tid >> 6, l = tid & 63;
  int p0 = blockIdx.x * 64;
  if (tid < 128) {
    int side = tid >> 6, r = tid & 63;
    int p = p0 + r;
    if (p >= P) p = P - 1;
    ynode[side][r] = y[2 * p + side];
  }
  __syncthreads();

  f32x4 acc[16];
#pragma unroll
  for (int c = 0; c < 16; ++c) acc[c] = (f32x4)(0.f);

  int arow = w * 16 + (l & 15);
  int akg = l >> 4;
  size_t bkoff = (size_t)akg * 8;

  for (int kt = 0; kt < 16; ++kt) {
    int k0 = kt * 32;
    const ushortT* shi;
    const ushortT* slo;
    int node, kk;
    if (kt < 8) { shi = XLhi; slo = XLlo; node = ynode[0][arow]; kk = k0; }
    else        { shi = XRhi; slo = XRlo; node = ynode[1][arow]; kk = k0 - 256; }
    size_t aoff = (size_t)node * HH + kk + akg * 8;
    gld16(shi + aoff, smem + w * 1024);
    gld16(slo + aoff, smem + 4096 + w * 1024);
#pragma unroll
    for (int r = 0; r < 4; ++r) {
      int colc = (r * 4 + w) * 16 + (l & 15);
      size_t boff = (size_t)colc * 512 + k0 + bkoff;
      gld16(Bhi + boff, smem + 8192 + r * 4096 + w * 1024);
      gld16(Blo + boff, smem + 24576 + r * 4096 + w * 1024);
    }
    __syncthreads();
    bf16x8 ah = *(const bf16x8*)(smem + tid * 16);
    bf16x8 al = *(const bf16x8*)(smem + 4096 + tid * 16);
#pragma unroll
    for (int c = 0; c < 16; ++c) {
      bf16x8 bh = *(const bf16x8*)(smem + 8192 + (c * 64 + l) * 16);
      bf16x8 bl = *(const bf16x8*)(smem + 24576 + (c * 64 + l) * 16);
      acc[c] = __builtin_amdgcn_mfma_f32_16x16x32_bf16(ah, bh, acc[c], 0, 0, 0);
      acc[c] = __builtin_amdgcn_mfma_f32_16x16x32_bf16(al, bh, acc[c], 0, 0, 0);
      acc[c] = __builtin_amdgcn_mfma_f32_16x16x32_bf16(ah, bl, acc[c], 0, 0, 0);
    }
    __syncthreads();
  }
  // epilogue: bias+relu, dot w2 across cols; reduce over 16 lanes of each row group
  float part[4] = {0.f, 0.f, 0.f, 0.f};
  int cb = l & 15;
#pragma unroll
  for (int c = 0; c < 16; ++c) {
    int colc = c * 16 + cb;
    float bv = fcb[colc];
    float wv = w2[colc];
#pragma unroll
    for (int r = 0; r < 4; ++r) part[r] += fmaxf(acc[c][r] + bv, 0.f) * wv;
  }
  float bias2 = b2[0];
#pragma unroll
  for (int r = 0; r < 4; ++r) {
    float s = part[r];
    s += __shfl_xor(s, 1);
    s += __shfl_xor(s, 2);
    s += __shfl_xor(s, 4);
    s += __shfl_xor(s, 8);
    if ((l & 15) == 0) {
      int p = p0 + w * 16 + (l >> 4) * 4 + r;
      if (p < P) out[p] = 1.f / (1.f + expf(-(s + bias2)));
    }
  }
}

// ---------------- launch ----------------

extern "C" void kernel_launch(void* const* d_in, const int* in_sizes, int n_in,
                              void* d_out, int out_size, void* d_ws, size_t ws_size,
                              hipStream_t stream) {
  const float* x_s  = (const float*)d_in[0];
  const float* x_t  = (const float*)d_in[1];
  const int*   ei_s = (const int*)d_in[2];
  const int*   ei_t = (const int*)d_in[3];
  const int*   y    = (const int*)d_in[4];
  const float* W1   = (const float*)d_in[5];
  const float* b1   = (const float*)d_in[6];
  const float* W2   = (const float*)d_in[7];
  const float* b2   = (const float*)d_in[8];
  const float* fcW  = (const float*)d_in[9];
  const float* fcb  = (const float*)d_in[10];
  const float* fc2W = (const float*)d_in[11];
  const float* fc2b = (const float*)d_in[12];
  float* out = (float*)d_out;

  char* ws = (char*)d_ws;
  size_t off = 0;
  auto alloc = [&](size_t bytes) -> void* {
    void* p = ws + off;
    off += (bytes + 255) & ~(size_t)255;
    return p;
  };
  float* Hbuf      = (float*)alloc((size_t)NN * HH * 4);
  ushortT* tmp_hi  = (ushortT*)alloc((size_t)NN * HH * 2);
  ushortT* tmp_lo  = (ushortT*)alloc((size_t)NN * HH * 2);
  ushortT* xl_hi   = (ushortT*)alloc((size_t)NN * HH * 2);
  ushortT* xl_lo   = (ushortT*)alloc((size_t)NN * HH * 2);
  ushortT* xr_hi   = (ushortT*)alloc((size_t)NN * HH * 2);
  ushortT* xr_lo   = (ushortT*)alloc((size_t)NN * HH * 2);
  ushortT* xa_hi   = (ushortT*)alloc((size_t)NN * DIN * 2);
  ushortT* xa_lo   = (ushortT*)alloc((size_t)NN * DIN * 2);
  ushortT* W1t_hi  = (ushortT*)alloc((size_t)HH * DIN * 2);
  ushortT* W1t_lo  = (ushortT*)alloc((size_t)HH * DIN * 2);
  ushortT* W2t_hi  = (ushortT*)alloc((size_t)HH * HH * 2);
  ushortT* W2t_lo  = (ushortT*)alloc((size_t)HH * HH * 2);
  ushortT* fct_hi  = (ushortT*)alloc((size_t)HH * 512 * 2);
  ushortT* fct_lo  = (ushortT*)alloc((size_t)HH * 512 * 2);
  int* cnt_s    = (int*)alloc((size_t)NN * 4);
  int* cnt_t    = (int*)alloc((size_t)NN * 4);
  float* dinv_s = (float*)alloc((size_t)NN * 4);
  float* dinv_t = (float*)alloc((size_t)NN * 4);
  int* indptr_s = (int*)alloc((size_t)(NN + 1) * 4);
  int* indptr_t = (int*)alloc((size_t)(NN + 1) * 4);
  int* fill_s   = (int*)alloc((size_t)NN * 4);
  int* fill_t   = (int*)alloc((size_t)NN * 4);
  int* col_s    = (int*)alloc((size_t)EE * 4);
  int* col_t    = (int*)alloc((size_t)EE * 4);
  int* bsum     = (int*)alloc(1024 * 4);

  hipMemsetAsync(cnt_s, 0, (size_t)NN * 4, stream);
  hipMemsetAsync(cnt_t, 0, (size_t)NN * 4, stream);
  hipMemsetAsync(fill_s, 0, (size_t)NN * 4, stream);
  hipMemsetAsync(fill_t, 0, (size_t)NN * 4, stream);

  const int NB = (NN + 255) / 256;
  const int EB = (EE + 255) / 256;

  // weight splits (tiny)
  split_w_t<<<(DIN * HH + 255) / 256, 256, 0, stream>>>(W1, W1t_hi, W1t_lo, DIN);
  split_w_t<<<(HH * HH + 255) / 256, 256, 0, stream>>>(W2, W2t_hi, W2t_lo, HH);
  split_w_t<<<(512 * HH + 255) / 256, 256, 0, stream>>>(fcW, fct_hi, fct_lo, 512);

  // CSR for both graphs
  count_deg<<<EB, 256, 0, stream>>>(ei_s + EE, cnt_s, EE);
  compute_dinv<<<NB, 256, 0, stream>>>(cnt_s, dinv_s, NN);
  scan_block<<<NB, 256, 0, stream>>>(cnt_s, indptr_s, bsum, NN);
  scan_totals<<<1, 1, 0, stream>>>(bsum, NB);
  scan_add<<<NB, 256, 0, stream>>>(indptr_s, bsum, cnt_s, NN);
  fill_csr<<<EB, 256, 0, stream>>>(ei_s, ei_s + EE, indptr_s, fill_s, col_s, EE);
  count_deg<<<EB, 256, 0, stream>>>(ei_t + EE, cnt_t, EE);
  compute_dinv<<<NB, 256, 0, stream>>>(cnt_t, dinv_t, NN);
  scan_block<<<NB, 256, 0, stream>>>(cnt_t, indptr_t, bsum, NN);
  scan_totals<<<1, 1, 0, stream>>>(bsum, NB);
  scan_add<<<NB, 256, 0, stream>>>(indptr_t, bsum, cnt_t, NN);
  fill_csr<<<EB, 256, 0, stream>>>(ei_t, ei_t + EE, indptr_t, fill_t, col_t, EE);

  const int GB = (NN + 63) / 64;         // 782 gemm blocks
  const int AB = (NN * 64 + 255) / 256;  // aggregate: 1 wave/node
  const int XB = (NN * DIN / 4 + 255) / 256;

  // s tower
  split_x<<<XB, 256, 0, stream>>>(x_s, xa_hi, xa_lo, NN * DIN / 4);
  gemm_mfma<<<GB, 256, 0, stream>>>(xa_hi, xa_lo, W1t_hi, W1t_lo, Hbuf, NN, DIN);
  aggregate_bf<<<AB, 256, 0, stream>>>(Hbuf, indptr_s, col_s, dinv_s, b1, tmp_hi, tmp_lo, NN);
  gemm_mfma<<<GB, 256, 0, stream>>>(tmp_hi, tmp_lo, W2t_hi, W2t_lo, Hbuf, NN, HH);
  aggregate_bf<<<AB, 256, 0, stream>>>(Hbuf, indptr_s, col_s, dinv_s, b2, xl_hi, xl_lo, NN);
  // t tower
  split_x<<<XB, 256, 0, stream>>>(x_t, xa_hi, xa_lo, NN * DIN / 4);
  gemm_mfma<<<GB, 256, 0, stream>>>(xa_hi, xa_lo, W1t_hi, W1t_lo, Hbuf, NN, DIN);
  aggregate_bf<<<AB, 256, 0, stream>>>(Hbuf, indptr_t, col_t, dinv_t, b1, tmp_hi, tmp_lo, NN);
  gemm_mfma<<<GB, 256, 0, stream>>>(tmp_hi, tmp_lo, W2t_hi, W2t_lo, Hbuf, NN, HH);
  aggregate_bf<<<AB, 256, 0, stream>>>(Hbuf, indptr_t, col_t, dinv_t, b2, xr_hi, xr_lo, NN);
  // fused pair MLP
  mlp_mfma<<<(PP + 63) / 64, 256, 0, stream>>>(xl_hi, xl_lo, xr_hi, xr_lo, y,
                                               fct_hi, fct_lo, fcb, fc2W, fc2b, out, PP);
}